// Round 3
// baseline (2591.436 us; speedup 1.0000x reference)
//
#include <hip/hip_runtime.h>
#include <math.h>
#include <float.h>
#include <limits.h>

// Problem constants
#define PIX     13824   // 64*216
#define QPIX    3456    // 32*108
#define QW      108
#define QH      32
#define NPTS    8192
#define MCAP    3072    // per-quadrant center capacity (expected ~2048, 26 sigma)
#define KTILES2 27      // QPIX/128
#define SPLITS  8       // center-range splits for k4a (round-robin tiles)
#define NCENT   (4*MCAP)  // 12288

// LDS swizzle: row-major 64-float rows, column rotated by 4*row (keeps float4
// groups contiguous & 16B aligned; read banks = padded-68 pattern, 0 pad bytes)
#define SW(row, col) (((row) << 6) + ((((col) + ((row) << 2))) & 63))

// ---------------------------------------------------------------------------
// K1: feat/value linear maps + fold to [r][k][c] pixel-major + feat inv-norm
// ---------------------------------------------------------------------------
__global__ __launch_bounds__(256) void k1_linmaps(
    const float* __restrict__ x, const float* __restrict__ Wf, const float* __restrict__ bf,
    const float* __restrict__ Wv, const float* __restrict__ bv,
    float* __restrict__ featp, float* __restrict__ valp, float* __restrict__ invn)
{
    __shared__ float ssq[4][64];
    int t = threadIdx.x;
    int lane = t & 63;
    int q = t >> 6;                       // wave id -> o-group (wave-uniform)
    int pix = blockIdx.x * 64 + lane;     // 216*64 = 13824 exact
    int h = pix / 216;
    int w = pix - h * 216;
    int r = ((h >> 5) << 1) | (w >= QW ? 1 : 0);
    int k = (h & 31) * QW + (w >= QW ? w - QW : w);

    float xr[64];
    #pragma unroll
    for (int c = 0; c < 64; c++) xr[c] = x[c * PIX + pix];

    size_t base = ((size_t)(r * QPIX + k)) * 64 + q * 16;
    float ss = 0.0f;
    for (int i = 0; i < 16; i++) {
        int o = q * 16 + i;               // wave-uniform
        float af = bf[o], av = bv[o];
        #pragma unroll
        for (int c = 0; c < 64; c++) {
            af = fmaf(Wf[o * 64 + c], xr[c], af);
            av = fmaf(Wv[o * 64 + c], xr[c], av);
        }
        featp[base + i] = af;
        valp[base + i]  = av;
        ss += af * af;
    }
    ssq[q][lane] = ss;
    __syncthreads();
    if (q == 0) {
        float tot = ssq[0][lane] + ssq[1][lane] + ssq[2][lane] + ssq[3][lane];
        invn[r * QPIX + k] = 1.0f / fmaxf(sqrtf(tot), 1e-12f);
    }
}

// ---------------------------------------------------------------------------
// K2 (hierarchical, order-preserving compaction)
// ---------------------------------------------------------------------------
__device__ __forceinline__ int point_quadrant(float px, float py) {
    return ((py > 192.0f) ? 2 : 0) + ((px > 648.0f) ? 1 : 0);
}

__global__ __launch_bounds__(64) void k2a_count(
    const float* __restrict__ points, int* __restrict__ ccnt)
{
    int lane = threadIdx.x;
    int chunk = blockIdx.x;
    float2 p = ((const float2*)points)[chunk * 64 + lane];
    int q = point_quadrant(p.x, p.y);
    #pragma unroll
    for (int r = 0; r < 4; r++) {
        unsigned long long m = __ballot(q == r);
        if (lane == 0) ccnt[chunk * 4 + r] = __popcll(m);
    }
}

__global__ __launch_bounds__(256) void k2b_scan(
    const int* __restrict__ ccnt, int* __restrict__ cbase, int* __restrict__ counts)
{
    int t = threadIdx.x;
    int r = t >> 6;        // wave = quadrant
    int lane = t & 63;     // lane handles chunks 2*lane, 2*lane+1
    int c0 = ccnt[(2 * lane) * 4 + r];
    int c1 = ccnt[(2 * lane + 1) * 4 + r];
    int pair = c0 + c1;
    int incl = pair;
    #pragma unroll
    for (int d = 1; d < 64; d <<= 1) {
        int n = __shfl_up(incl, d, 64);
        if (lane >= d) incl += n;
    }
    int excl = incl - pair;
    cbase[r * 128 + 2 * lane]     = excl;
    cbase[r * 128 + 2 * lane + 1] = excl + c0;
    if (lane == 63) counts[r] = incl;
}

__global__ __launch_bounds__(64) void k2c_scatter(
    const float* __restrict__ points, const int* __restrict__ cbase,
    float* __restrict__ cp, int* __restrict__ slot)
{
    int lane = threadIdx.x;
    int chunk = blockIdx.x;
    int n = chunk * 64 + lane;
    float2 p = ((const float2*)points)[n];
    int q = point_quadrant(p.x, p.y);
    unsigned long long below = (lane == 0) ? 0ull : (~0ull >> (64 - lane));
    #pragma unroll
    for (int r = 0; r < 4; r++) {
        unsigned long long m = __ballot(q == r);
        if (q == r) {
            int pos = cbase[r * 128 + chunk] + __popcll(m & below);
            ((float2*)cp)[r * MCAP + pos] = p;
            slot[n] = r * MCAP + pos;
        }
    }
}

// ---------------------------------------------------------------------------
// K3: bilinear gather (border clamp) of feat & value at compacted points;
// slot m == K_r is the phantom (0,0) padded row.
// ---------------------------------------------------------------------------
__global__ __launch_bounds__(64) void k3_gather(
    const float* __restrict__ featp, const float* __restrict__ valp,
    const float* __restrict__ cp, const int* __restrict__ counts,
    float* __restrict__ cn, float* __restrict__ vc)
{
    int r = blockIdx.y;
    int m = blockIdx.x * 64 + threadIdx.x;
    int K = counts[r];
    int Mr = min(K + 1, MCAP);
    if (m >= Mr) return;
    float px = 0.0f, py = 0.0f;
    if (m < K) { float2 p = ((const float2*)cp)[r * MCAP + m]; px = p.x; py = p.y; }

    float gx = (px / 1295.0f * 2.0f - 1.0f + 1.0f) * 54.0f - 0.5f;
    float gy = (py / 383.0f  * 2.0f - 1.0f + 1.0f) * 16.0f - 0.5f;
    float x0 = floorf(gx), y0 = floorf(gy);
    float wx = gx - x0, wy = gy - y0;
    int x0i = (int)fminf(fmaxf(x0,         0.0f), 107.0f);
    int x1i = (int)fminf(fmaxf(x0 + 1.0f,  0.0f), 107.0f);
    int y0i = (int)fminf(fmaxf(y0,         0.0f), 31.0f);
    int y1i = (int)fminf(fmaxf(y0 + 1.0f,  0.0f), 31.0f);
    float w00 = (1.0f - wx) * (1.0f - wy);
    float w01 = wx * (1.0f - wy);
    float w10 = (1.0f - wx) * wy;
    float w11 = wx * wy;

    size_t b00 = ((size_t)(r * QPIX + y0i * QW + x0i)) * 64;
    size_t b01 = ((size_t)(r * QPIX + y0i * QW + x1i)) * 64;
    size_t b10 = ((size_t)(r * QPIX + y1i * QW + x0i)) * 64;
    size_t b11 = ((size_t)(r * QPIX + y1i * QW + x1i)) * 64;
    size_t ob  = ((size_t)(r * MCAP + m)) * 64;

    float fr[64];
    float ss = 0.0f;
    #pragma unroll
    for (int c = 0; c < 64; c += 4) {
        float4 a  = *(const float4*)(featp + b00 + c);
        float4 b_ = *(const float4*)(featp + b01 + c);
        float4 g  = *(const float4*)(featp + b10 + c);
        float4 d  = *(const float4*)(featp + b11 + c);
        float e0 = a.x * w00 + b_.x * w01 + g.x * w10 + d.x * w11;
        float e1 = a.y * w00 + b_.y * w01 + g.y * w10 + d.y * w11;
        float e2 = a.z * w00 + b_.z * w01 + g.z * w10 + d.z * w11;
        float e3 = a.w * w00 + b_.w * w01 + g.w * w10 + d.w * w11;
        fr[c] = e0; fr[c+1] = e1; fr[c+2] = e2; fr[c+3] = e3;
        ss += e0*e0; ss += e1*e1; ss += e2*e2; ss += e3*e3;
    }
    float inv = 1.0f / fmaxf(sqrtf(ss), 1e-12f);
    #pragma unroll
    for (int c = 0; c < 64; c += 4) {
        *(float4*)(cn + ob + c) =
            make_float4(fr[c]*inv, fr[c+1]*inv, fr[c+2]*inv, fr[c+3]*inv);
    }
    #pragma unroll
    for (int c = 0; c < 64; c += 4) {
        float4 a  = *(const float4*)(valp + b00 + c);
        float4 b_ = *(const float4*)(valp + b01 + c);
        float4 g  = *(const float4*)(valp + b10 + c);
        float4 d  = *(const float4*)(valp + b11 + c);
        float4 o;
        o.x = a.x * w00 + b_.x * w01 + g.x * w10 + d.x * w11;
        o.y = a.y * w00 + b_.y * w01 + g.y * w10 + d.y * w11;
        o.z = a.z * w00 + b_.z * w01 + g.z * w10 + d.z * w11;
        o.w = a.w * w00 + b_.w * w01 + g.w * w10 + d.w * w11;
        *(float4*)(vc + ob + c) = o;
    }
}

// ---------------------------------------------------------------------------
// K4a: cosine-sim running argmax, 128 keys x 128 centers tile, 8x8/thread.
// LDS bytes/FMA = 1.0 (vs 2.0 at 4x4) -> LDS-pipe floor ~35us.
// Round-robin center tiles over SPLITS (m stays ascending per thread).
// ---------------------------------------------------------------------------
__global__ __launch_bounds__(256, 2) void k4a_sim(
    const float* __restrict__ featp, const float* __restrict__ invn,
    const float* __restrict__ cn, const int* __restrict__ counts,
    const float* __restrict__ alpha_p, const float* __restrict__ beta_p,
    float* __restrict__ part_s, int* __restrict__ part_m)
{
    __shared__ float A[128 * 64];   // centers tile (reused for rs reduction)
    __shared__ float B[128 * 64];   // keys tile   (reused for rm reduction)

    int r     = blockIdx.z;
    int kt    = blockIdx.x;
    int split = blockIdx.y;
    int k0 = kt * 128;
    int t  = threadIdx.x;
    int tx = t & 15, ty = t >> 4;
    int K  = counts[r];
    int Mr = min(K + 1, MCAP);
    float alpha = alpha_p[0], beta = beta_p[0];

    // stage B: 128 keys x 64 ch, normalized; thread: row t>>1, half t&1
    {
        int row = t >> 1, half = t & 1;
        float inv = invn[r * QPIX + k0 + row];
        const float* src = featp + ((size_t)(r * QPIX + k0 + row)) * 64 + half * 32;
        #pragma unroll
        for (int i = 0; i < 8; i++) {
            float4 fv = ((const float4*)src)[i];
            fv.x *= inv; fv.y *= inv; fv.z *= inv; fv.w *= inv;
            *(float4*)(B + SW(row, half * 32 + i * 4)) = fv;
        }
    }

    float bs[8]; int bm[8];
    #pragma unroll
    for (int v = 0; v < 8; v++) { bs[v] = -INFINITY; bm[v] = INT_MAX; }

    int ntiles = (Mr + 127) >> 7;
    for (int ct = split; ct < ntiles; ct += SPLITS) {
        __syncthreads();   // prev tile's A reads done (first iter: covers B stage)
        {
            int row = t >> 1, half = t & 1;
            int mg = min(ct * 128 + row, MCAP - 1);
            const float* src = cn + ((size_t)(r * MCAP + mg)) * 64 + half * 32;
            #pragma unroll
            for (int i = 0; i < 8; i++)
                *(float4*)(A + SW(row, half * 32 + i * 4)) = ((const float4*)src)[i];
        }
        __syncthreads();

        float dot[8][8];
        #pragma unroll
        for (int u = 0; u < 8; u++)
            #pragma unroll
            for (int v = 0; v < 8; v++) dot[u][v] = 0.0f;

        #pragma unroll
        for (int cc = 0; cc < 64; cc += 4) {
            int ac = (cc + 4 * ty) & 63;   // swizzled col, u-independent (64u wraps)
            int bc = (cc + 4 * tx) & 63;
            float4 av[8], bv[8];
            #pragma unroll
            for (int u = 0; u < 8; u++) av[u] = *(const float4*)(A + ((ty + 16*u) << 6) + ac);
            #pragma unroll
            for (int v = 0; v < 8; v++) bv[v] = *(const float4*)(B + ((tx + 16*v) << 6) + bc);
            #pragma unroll
            for (int u = 0; u < 8; u++) {
                #pragma unroll
                for (int v = 0; v < 8; v++) {
                    dot[u][v] = fmaf(av[u].x, bv[v].x, dot[u][v]);
                    dot[u][v] = fmaf(av[u].y, bv[v].y, dot[u][v]);
                    dot[u][v] = fmaf(av[u].z, bv[v].z, dot[u][v]);
                    dot[u][v] = fmaf(av[u].w, bv[v].w, dot[u][v]);
                }
            }
        }
        // running argmax; m ascending (u asc, ct asc); strict > keeps smallest m
        #pragma unroll
        for (int u = 0; u < 8; u++) {
            int mg = ct * 128 + ty + 16 * u;
            bool valid = mg < Mr;
            #pragma unroll
            for (int v = 0; v < 8; v++) {
                float s = fmaf(alpha, dot[u][v], beta);  // monotone w/ sigmoid
                if (valid && s > bs[v]) { bs[v] = s; bm[v] = mg; }
            }
        }
    }

    // cross-thread (ty) reduce per key; tie -> smaller m. Reuse A/B space.
    float* rs = A;          // [16][17]
    int*   rm = (int*)B;    // [16][17]
    size_t pb = ((size_t)((r * KTILES2 + kt) * SPLITS + split)) * 128;
    #pragma unroll
    for (int v = 0; v < 8; v++) {
        __syncthreads();
        rs[ty * 17 + tx] = bs[v]; rm[ty * 17 + tx] = bm[v];
        __syncthreads();
        for (int st = 8; st > 0; st >>= 1) {
            if (ty < st) {
                float s2 = rs[(ty + st) * 17 + tx]; int m2 = rm[(ty + st) * 17 + tx];
                if (s2 > rs[ty * 17 + tx] ||
                    (s2 == rs[ty * 17 + tx] && m2 < rm[ty * 17 + tx])) {
                    rs[ty * 17 + tx] = s2; rm[ty * 17 + tx] = m2;
                }
            }
            __syncthreads();
        }
        if (ty == 0) { part_s[pb + tx + 16 * v] = rs[tx]; part_m[pb + tx + 16 * v] = rm[tx]; }
    }
}

// ---------------------------------------------------------------------------
// K4b: per-key winner (reduce splits), sigmoid weight, count per center.
// ---------------------------------------------------------------------------
__global__ __launch_bounds__(256) void k4b_win(
    const float* __restrict__ part_s, const int* __restrict__ part_m,
    const int* __restrict__ counts,
    int* __restrict__ win_m, float* __restrict__ win_w, int* __restrict__ cnt)
{
    int g = blockIdx.x * 256 + threadIdx.x;   // 0..13823
    int r = g / 3456, kk = g - r * 3456;
    int kt = kk >> 7, j = kk & 127;
    size_t base = ((size_t)((r * KTILES2 + kt) * SPLITS)) * 128 + j;
    float bs = -INFINITY; int bm = INT_MAX;
    #pragma unroll
    for (int s = 0; s < SPLITS; s++) {
        float s2 = part_s[base + (size_t)s * 128];
        int   m2 = part_m[base + (size_t)s * 128];
        if (s2 > bs || (s2 == bs && m2 < bm)) { bs = s2; bm = m2; }
    }
    int K = counts[r];
    if (bm < K) {
        int cg = r * MCAP + bm;
        win_m[g] = cg;
        win_w[g] = 1.0f / (1.0f + expf(-bs));
        atomicAdd(cnt + cg, 1);
    } else {
        win_m[g] = -1;
    }
}

// ---------------------------------------------------------------------------
// K4c: exclusive scan of cnt[12288] -> offs, cursor (single block, 1024 thr)
// ---------------------------------------------------------------------------
__global__ __launch_bounds__(1024) void k4c_scan(
    const int* __restrict__ cnt, int* __restrict__ offs, int* __restrict__ cursor)
{
    __shared__ int wt[16];
    __shared__ int wbase[16];
    int t = threadIdx.x;
    int lane = t & 63, w = t >> 6;
    int base = t * 12;
    int pre[12];
    int tot = 0;
    #pragma unroll
    for (int i = 0; i < 12; i++) { pre[i] = tot; tot += cnt[base + i]; }
    int incl = tot;
    #pragma unroll
    for (int d = 1; d < 64; d <<= 1) {
        int n = __shfl_up(incl, d, 64);
        if (lane >= d) incl += n;
    }
    if (lane == 63) wt[w] = incl;
    __syncthreads();
    if (t < 16) {
        int x = wt[t], inc = x;
        #pragma unroll
        for (int d = 1; d < 16; d <<= 1) {
            int n = __shfl_up(inc, d, 64);
            if (t >= d) inc += n;
        }
        wbase[t] = inc - x;
    }
    __syncthreads();
    int texcl = wbase[w] + incl - tot;
    #pragma unroll
    for (int i = 0; i < 12; i++) {
        int o = texcl + pre[i];
        offs[base + i] = o;
        cursor[base + i] = o;
    }
}

// ---------------------------------------------------------------------------
// K4d: fill member lists (1 small atomic per key)
// ---------------------------------------------------------------------------
__global__ __launch_bounds__(256) void k4d_fill(
    const int* __restrict__ win_m, const float* __restrict__ win_w,
    int* __restrict__ cursor, int* __restrict__ memb_row, float* __restrict__ memb_w)
{
    int g = blockIdx.x * 256 + threadIdx.x;
    int cg = win_m[g];
    if (cg >= 0) {
        int pos = atomicAdd(cursor + cg, 1);
        int r = g / 3456, kk = g - r * 3456;
        memb_row[pos] = r * QPIX + kk;
        memb_w[pos] = win_w[g];
    }
}

// ---------------------------------------------------------------------------
// K4e: per-center gather-aggregate (no atomics). Wave = center, lane = channel.
// Writes every agg/denom row (removes the big memset).
// ---------------------------------------------------------------------------
__global__ __launch_bounds__(256) void k4e_agg(
    const int* __restrict__ offs, const int* __restrict__ cnt,
    const int* __restrict__ memb_row, const float* __restrict__ memb_w,
    const float* __restrict__ valp,
    float* __restrict__ agg, float* __restrict__ denom)
{
    int ci = blockIdx.x * 4 + (threadIdx.x >> 6);
    int c  = threadIdx.x & 63;
    int start = offs[ci], len = cnt[ci];
    float acc = 0.0f, den = 0.0f;
    for (int j = 0; j < len; j++) {
        int row = memb_row[start + j];      // wave-uniform broadcast load
        float w = memb_w[start + j];
        acc = fmaf(w, valp[(size_t)row * 64 + c], acc);
        den += w;
    }
    agg[(size_t)ci * 64 + c] = acc;
    if (c == 0) denom[ci] = den;
}

// ---------------------------------------------------------------------------
// K5: per-point output + projection + transposed store [1,64,1,8192].
// Block = 16 points (4 waves x 4 pts); lane c holds Wp row c in registers;
// dot via __shfl broadcast of the wave's own o_v lanes. Full-line stores.
// ---------------------------------------------------------------------------
__global__ __launch_bounds__(256) void k5_out(
    const float* __restrict__ agg, const float* __restrict__ vc,
    const float* __restrict__ denom, const int* __restrict__ slot,
    const float* __restrict__ Wp, const float* __restrict__ bp,
    float* __restrict__ out)
{
    __shared__ float res[16][64];
    int t = threadIdx.x;
    int wv = t >> 6, c = t & 63;
    int n0 = blockIdx.x * 16;

    float4 wr[16];
    #pragma unroll
    for (int q = 0; q < 16; q++) wr[q] = ((const float4*)(Wp + c * 64))[q];
    float bpc = bp[c];

    #pragma unroll
    for (int i = 0; i < 4; i++) {
        int n = n0 + wv * 4 + i;
        int sl = slot[n];
        float d = denom[sl] + 1.0f;
        float o_v = (agg[(size_t)sl * 64 + c] + vc[(size_t)sl * 64 + c]) / d;
        unsigned long long nz = __ballot(o_v != 0.0f);   // wave == point
        float acc = bpc;
        #pragma unroll
        for (int q = 0; q < 16; q++) {
            acc = fmaf(__shfl(o_v, 4 * q + 0, 64), wr[q].x, acc);
            acc = fmaf(__shfl(o_v, 4 * q + 1, 64), wr[q].y, acc);
            acc = fmaf(__shfl(o_v, 4 * q + 2, 64), wr[q].z, acc);
            acc = fmaf(__shfl(o_v, 4 * q + 3, 64), wr[q].w, acc);
        }
        res[wv * 4 + i][c] = (nz != 0ull) ? acc : 0.0f;
    }
    __syncthreads();
    // transposed store: thread (row=t&63, seg=t>>6) writes 16B of row; 4 waves
    // cover a full 64B line per row.
    int row = t & 63, seg = t >> 6;
    float4 val = make_float4(res[seg * 4 + 0][row], res[seg * 4 + 1][row],
                             res[seg * 4 + 2][row], res[seg * 4 + 3][row]);
    *(float4*)(out + (size_t)row * NPTS + n0 + seg * 4) = val;
}

// ---------------------------------------------------------------------------
extern "C" void kernel_launch(void* const* d_in, const int* in_sizes, int n_in,
                              void* d_out, int out_size, void* d_ws, size_t ws_size,
                              hipStream_t stream) {
    const float* points = (const float*)d_in[0];
    const float* x      = (const float*)d_in[1];
    const float* Wf     = (const float*)d_in[2];
    const float* bf     = (const float*)d_in[3];
    const float* Wv     = (const float*)d_in[4];
    const float* bv     = (const float*)d_in[5];
    const float* Wp     = (const float*)d_in[6];
    const float* bp     = (const float*)d_in[7];
    const float* alpha  = (const float*)d_in[8];
    const float* beta   = (const float*)d_in[9];
    float* out = (float*)d_out;

    float* ws     = (float*)d_ws;
    float* featp  = ws;                          // 884736
    float* valp   = featp + 884736;              // 884736
    float* cn     = valp  + 884736;              // 786432 (4*MCAP*64)
    float* vc     = cn    + 786432;              // 786432
    float* agg    = vc    + 786432;              // 786432
    float* denom  = agg   + 786432;              // 12288
    float* invn   = denom + 12288;               // 13824
    float* cp     = invn  + 13824;               // 24576
    float* part_s = cp    + 24576;               // 110592 (4*27*8*128)
    int*   part_m = (int*)(part_s + 110592);     // 110592
    int*   ccnt   = part_m + 110592;             // 512
    int*   cbase  = ccnt   + 512;                // 512
    int*   counts = cbase  + 512;                // 16
    int*   slot   = counts + 16;                 // 8192
    int*   win_m  = slot   + 8192;               // 13824
    float* win_w  = (float*)(win_m + 13824);     // 13824
    int*   cnt    = (int*)(win_w + 13824);       // 12288
    int*   offs   = cnt    + 12288;              // 12288
    int*   cursor = offs   + 12288;              // 12288
    int*   memb_row = cursor + 12288;            // 13824
    float* memb_w = (float*)(memb_row + 13824);  // 13824
    // total ~14.6 MB of d_ws

    // only cnt needs zero-init now (ws is poisoned every launch)
    hipMemsetAsync(cnt, 0, (size_t)NCENT * sizeof(int), stream);

    k1_linmaps<<<216, 256, 0, stream>>>(x, Wf, bf, Wv, bv, featp, valp, invn);
    k2a_count  <<<128, 64, 0, stream>>>(points, ccnt);
    k2b_scan   <<<1, 256, 0, stream>>>(ccnt, cbase, counts);
    k2c_scatter<<<128, 64, 0, stream>>>(points, cbase, cp, slot);
    k3_gather<<<dim3(MCAP / 64, 4), 64, 0, stream>>>(featp, valp, cp, counts, cn, vc);
    k4a_sim<<<dim3(KTILES2, SPLITS, 4), 256, 0, stream>>>(featp, invn, cn, counts,
                                                          alpha, beta, part_s, part_m);
    k4b_win<<<54, 256, 0, stream>>>(part_s, part_m, counts, win_m, win_w, cnt);
    k4c_scan<<<1, 1024, 0, stream>>>(cnt, offs, cursor);
    k4d_fill<<<54, 256, 0, stream>>>(win_m, win_w, cursor, memb_row, memb_w);
    k4e_agg<<<NCENT / 4, 256, 0, stream>>>(offs, cnt, memb_row, memb_w, valp, agg, denom);
    k5_out<<<NPTS / 16, 256, 0, stream>>>(agg, vc, denom, slot, Wp, bp, out);
}